// Round 3
// baseline (420.827 us; speedup 1.0000x reference)
//
#include <hip/hip_runtime.h>
#include <stdint.h>

// Problem constants (fixed by reference):
//   N=16384 spatial, R=16 feat, P=4096 blocks, T=64 out-feat, B=8 batch
#define C_N 16384
#define C_R 16
#define C_P 4096
#define C_B 8

// R2: latency-bound fix. Weight loads become 1 KB global_load_dwordx4
// (lane l=16g+m reads rows 4j+g, cols 4m..4m+3), rolling depth-8 pipeline
// -> 16 KB in flight per wave (was 2 KB). Each lane accumulates 4 output
// cols x 8 batches over its row subset (i === g mod 4); one 2-step
// __shfl_xor(16/32) reduction at the end. Perm via uniform scalar load;
// x global loads issued BEFORE the weight prologue so the pre-barrier
// wait only covers x, and weight DMA latency hides under staging+barrier.
__global__ __launch_bounds__(128)
void butterfly_local_conv(const float* __restrict__ x,
                          const float* __restrict__ Wrr,
                          const float* __restrict__ Wri,
                          const float* __restrict__ Wir,
                          const float* __restrict__ Wii,
                          const int*   __restrict__ perm,
                          float* __restrict__ out)
{
    __shared__ float xs[2][C_B][64];   // 4 KB: [c][b][i], i = s*16 + r

    const int t    = threadIdx.x;
    const int lane = t & 63;
    const int half = t >> 6;           // wave 0 -> y_re, wave 1 -> y_im
    const int p    = blockIdx.x;
    const int g    = lane >> 4;        // row phase 0..3 (i === g mod 4)
    const int m    = lane & 15;        // col quad: o = 4m..4m+3

    // ---- perm: wave-uniform scalar load (no per-thread VMEM, no vmcnt)
    const int4 pv = *(const int4*)(perm + 4 * p);

    // ---- x gather: issue the 2 float4 loads FIRST (oldest in vmcnt order)
    float4 xv[2];
    int    lidx[2];
    #pragma unroll
    for (int j = 0; j < 2; ++j) {
        const int idx = t * 2 + j;             // 0..255
        const int c = idx >> 7;                // re/im component
        const int b = (idx >> 4) & 7;          // batch
        const int s = (idx >> 2) & 3;          // window position
        const int q = idx & 3;                 // float4 within row of 16
        const int n = (s & 2) ? ((s & 1) ? pv.w : pv.z)
                              : ((s & 1) ? pv.y : pv.x);
        xv[j] = ((const float4*)(x + (((size_t)(b * 2 + c)) * C_N + n) * C_R))[q];
        lidx[j] = c * 512 + b * 64 + s * 16 + q * 4;   // dword index into xs
    }

    // ---- weight streaming: per-lane base at dword 4*lane within the p-block
    const float* __restrict__ WAp = (half ? Wir : Wrr) + (size_t)p * 4096 + 4 * lane;
    const float* __restrict__ WBp = (half ? Wii : Wri) + (size_t)p * 4096 + 4 * lane;

    // prologue: chunks 0..7 in flight (16 x 1KB dwordx4 = 16 KB/wave)
    float4 A[8], B[8];
    #pragma unroll
    for (int j = 0; j < 8; ++j) {
        A[j] = *(const float4*)(WAp + 256 * j);
        B[j] = *(const float4*)(WBp + 256 * j);
    }

    // ---- commit x to LDS (waits only the x loads; weight queue stays live)
    *(float4*)((float*)xs + lidx[0]) = xv[0];
    *(float4*)((float*)xs + lidx[1]) = xv[1];
    __syncthreads();

    // ---- main loop: 16 chunks of 4 rows, rolling depth-8 prefetch.
    // x ds_read: 4 distinct consecutive dwords per wave (16-lane broadcast
    // each) -> conflict-free. All buffer indices compile-time (full unroll).
    float4 acc[C_B];
    #pragma unroll
    for (int b = 0; b < C_B; ++b) acc[b] = make_float4(0.f, 0.f, 0.f, 0.f);

    const float* xsg = &xs[0][0][0] + g;   // per-lane LDS base (dword +g)

    #pragma unroll
    for (int j = 0; j < 16; ++j) {
        const float4 a = A[j & 7];
        const float4 w = B[j & 7];
        #pragma unroll
        for (int b = 0; b < C_B; ++b) {
            const float xr = xsg[b * 64 + 4 * j];          // xs[0][b][4j+g]
            const float xi = xsg[512 + b * 64 + 4 * j];    // xs[1][b][4j+g]
            acc[b].x = fmaf(xr, a.x, acc[b].x);
            acc[b].y = fmaf(xr, a.y, acc[b].y);
            acc[b].z = fmaf(xr, a.z, acc[b].z);
            acc[b].w = fmaf(xr, a.w, acc[b].w);
            acc[b].x = fmaf(xi, w.x, acc[b].x);
            acc[b].y = fmaf(xi, w.y, acc[b].y);
            acc[b].z = fmaf(xi, w.z, acc[b].z);
            acc[b].w = fmaf(xi, w.w, acc[b].w);
        }
        if (j + 8 < 16) {   // prefetch chunk j+8 into the slot just consumed
            A[j & 7] = *(const float4*)(WAp + 256 * (j + 8));
            B[j & 7] = *(const float4*)(WBp + 256 * (j + 8));
        }
    }

    // ---- cross-group reduction: sum over g (lanes l, l^16, l^32, l^48)
    #pragma unroll
    for (int b = 0; b < C_B; ++b) {
        acc[b].x += __shfl_xor(acc[b].x, 16); acc[b].x += __shfl_xor(acc[b].x, 32);
        acc[b].y += __shfl_xor(acc[b].y, 16); acc[b].y += __shfl_xor(acc[b].y, 32);
        acc[b].z += __shfl_xor(acc[b].z, 16); acc[b].z += __shfl_xor(acc[b].z, 32);
        acc[b].w += __shfl_xor(acc[b].w, 16); acc[b].w += __shfl_xor(acc[b].w, 32);
    }

    // ---- store: group g writes batches 2g, 2g+1 (static acc indices via
    // cndmask selects -- no runtime-indexed register array, rule #20)
    const float4 s0 = (g == 0) ? acc[0] : (g == 1) ? acc[2] : (g == 2) ? acc[4] : acc[6];
    const float4 s1 = (g == 0) ? acc[1] : (g == 1) ? acc[3] : (g == 2) ? acc[5] : acc[7];
    const size_t obase = (size_t)p * 64 + 4 * m;
    const int b0 = g * 2;
    *(float4*)(out + ((size_t)(b0 * 2 + half)) * (C_N * C_R) + obase) = s0;
    *(float4*)(out + ((size_t)((b0 + 1) * 2 + half)) * (C_N * C_R) + obase) = s1;
}

extern "C" void kernel_launch(void* const* d_in, const int* in_sizes, int n_in,
                              void* d_out, int out_size, void* d_ws, size_t ws_size,
                              hipStream_t stream) {
    const float* x    = (const float*)d_in[0];
    const float* Wrr  = (const float*)d_in[1];
    const float* Wri  = (const float*)d_in[2];
    const float* Wir  = (const float*)d_in[3];
    const float* Wii  = (const float*)d_in[4];
    const int*   perm = (const int*)d_in[5];
    float* out = (float*)d_out;

    // One 128-thread WG (2 waves: re half, im half) per block p.
    butterfly_local_conv<<<dim3(C_P), dim3(128), 0, stream>>>(
        x, Wrr, Wri, Wir, Wii, perm, out);
}

// Round 4
// 366.608 us; speedup vs baseline: 1.1479x; 1.1479x over previous
//
#include <hip/hip_runtime.h>
#include <stdint.h>

// Problem constants (fixed by reference):
//   N=16384 spatial, R=16 feat, P=4096 blocks, T=64 out-feat, B=8 batch
#define C_N 16384
#define C_R 16
#define C_P 4096
#define C_B 8

// R3: R2 structure (coalesced 1 KB dwordx4 weight loads, lane l=16g+m,
// per-lane 4 output cols x 8 batches, shfl_xor(16/32) reduction) but
// pipeline depth cut 8 -> 4 and VGPRs pinned via __launch_bounds__(128,4).
// R2's depth-8 needed ~130 VGPRs, compiler allocated 72 -> spilled the
// stream buffers to scratch every chunk (WRITE_SIZE 16 MB -> 305 MB).
// Depth-4 peak ~80 VGPRs: 32 (4x2 float4 slots) + 32 (acc) + addressing.
// Steady in-flight: 3-4 chunks x 2 KB = 6-8 KB/wave, 3-4x R1's depth at
// 1/4 the load-instruction count.
__global__ __launch_bounds__(128, 4)
void butterfly_local_conv(const float* __restrict__ x,
                          const float* __restrict__ Wrr,
                          const float* __restrict__ Wri,
                          const float* __restrict__ Wir,
                          const float* __restrict__ Wii,
                          const int*   __restrict__ perm,
                          float* __restrict__ out)
{
    __shared__ float xs[2][C_B][64];   // 4 KB: [c][b][i], i = s*16 + r

    const int t    = threadIdx.x;
    const int lane = t & 63;
    const int half = t >> 6;           // wave 0 -> y_re, wave 1 -> y_im
    const int p    = blockIdx.x;
    const int g    = lane >> 4;        // row phase 0..3 (i === g mod 4)
    const int m    = lane & 15;        // col quad: o = 4m..4m+3

    // ---- perm: wave-uniform scalar load (no per-thread VMEM)
    const int4 pv = *(const int4*)(perm + 4 * p);

    // ---- x gather: issue the 2 float4 loads FIRST (oldest in vmcnt order,
    // so the pre-barrier ds_write waits only on these, not the weight queue)
    float4 xv[2];
    int    lidx[2];
    #pragma unroll
    for (int j = 0; j < 2; ++j) {
        const int idx = t * 2 + j;             // 0..255
        const int c = idx >> 7;                // re/im component
        const int b = (idx >> 4) & 7;          // batch
        const int s = (idx >> 2) & 3;          // window position
        const int q = idx & 3;                 // float4 within row of 16
        const int n = (s & 2) ? ((s & 1) ? pv.w : pv.z)
                              : ((s & 1) ? pv.y : pv.x);
        xv[j] = ((const float4*)(x + (((size_t)(b * 2 + c)) * C_N + n) * C_R))[q];
        lidx[j] = c * 512 + b * 64 + s * 16 + q * 4;   // dword index into xs
    }

    // ---- weight streaming: per-lane base at dword 4*lane within the p-block
    const float* __restrict__ WAp = (half ? Wir : Wrr) + (size_t)p * 4096 + 4 * lane;
    const float* __restrict__ WBp = (half ? Wii : Wri) + (size_t)p * 4096 + 4 * lane;

    // prologue: chunks 0..3 in flight (8 x 1KB dwordx4 = 8 KB/wave)
    float4 A[4], B[4];
    #pragma unroll
    for (int j = 0; j < 4; ++j) {
        A[j] = *(const float4*)(WAp + 256 * j);
        B[j] = *(const float4*)(WBp + 256 * j);
    }

    // ---- commit x to LDS (vmcnt wait covers only the x loads; the
    // younger weight loads stay in flight across the barrier)
    *(float4*)((float*)xs + lidx[0]) = xv[0];
    *(float4*)((float*)xs + lidx[1]) = xv[1];
    __syncthreads();

    // ---- main loop: 16 chunks of 4 rows, rolling depth-4 prefetch.
    // x ds_read: 4 distinct consecutive dwords per wave (16-lane broadcast
    // each) -> conflict-free. All buffer indices compile-time (full unroll).
    float4 acc[C_B];
    #pragma unroll
    for (int b = 0; b < C_B; ++b) acc[b] = make_float4(0.f, 0.f, 0.f, 0.f);

    const float* xsg = &xs[0][0][0] + g;   // per-lane LDS base (dword +g)

    #pragma unroll
    for (int j = 0; j < 16; ++j) {
        const float4 a = A[j & 3];
        const float4 w = B[j & 3];
        #pragma unroll
        for (int b = 0; b < C_B; ++b) {
            const float xr = xsg[b * 64 + 4 * j];          // xs[0][b][4j+g]
            const float xi = xsg[512 + b * 64 + 4 * j];    // xs[1][b][4j+g]
            acc[b].x = fmaf(xr, a.x, acc[b].x);
            acc[b].y = fmaf(xr, a.y, acc[b].y);
            acc[b].z = fmaf(xr, a.z, acc[b].z);
            acc[b].w = fmaf(xr, a.w, acc[b].w);
            acc[b].x = fmaf(xi, w.x, acc[b].x);
            acc[b].y = fmaf(xi, w.y, acc[b].y);
            acc[b].z = fmaf(xi, w.z, acc[b].z);
            acc[b].w = fmaf(xi, w.w, acc[b].w);
        }
        if (j + 4 < 16) {   // prefetch chunk j+4 into the slot just freed
            A[j & 3] = *(const float4*)(WAp + 256 * (j + 4));
            B[j & 3] = *(const float4*)(WBp + 256 * (j + 4));
        }
    }

    // ---- cross-group reduction: sum over g (lanes l, l^16, l^32, l^48)
    #pragma unroll
    for (int b = 0; b < C_B; ++b) {
        acc[b].x += __shfl_xor(acc[b].x, 16); acc[b].x += __shfl_xor(acc[b].x, 32);
        acc[b].y += __shfl_xor(acc[b].y, 16); acc[b].y += __shfl_xor(acc[b].y, 32);
        acc[b].z += __shfl_xor(acc[b].z, 16); acc[b].z += __shfl_xor(acc[b].z, 32);
        acc[b].w += __shfl_xor(acc[b].w, 16); acc[b].w += __shfl_xor(acc[b].w, 32);
    }

    // ---- store: group g writes batches 2g, 2g+1 (static acc indices via
    // cndmask selects -- no runtime-indexed register array, rule #20)
    const float4 s0 = (g == 0) ? acc[0] : (g == 1) ? acc[2] : (g == 2) ? acc[4] : acc[6];
    const float4 s1 = (g == 0) ? acc[1] : (g == 1) ? acc[3] : (g == 2) ? acc[5] : acc[7];
    const size_t obase = (size_t)p * 64 + 4 * m;
    const int b0 = g * 2;
    *(float4*)(out + ((size_t)(b0 * 2 + half)) * (C_N * C_R) + obase) = s0;
    *(float4*)(out + ((size_t)((b0 + 1) * 2 + half)) * (C_N * C_R) + obase) = s1;
}

extern "C" void kernel_launch(void* const* d_in, const int* in_sizes, int n_in,
                              void* d_out, int out_size, void* d_ws, size_t ws_size,
                              hipStream_t stream) {
    const float* x    = (const float*)d_in[0];
    const float* Wrr  = (const float*)d_in[1];
    const float* Wri  = (const float*)d_in[2];
    const float* Wir  = (const float*)d_in[3];
    const float* Wii  = (const float*)d_in[4];
    const int*   perm = (const int*)d_in[5];
    float* out = (float*)d_out;

    // One 128-thread WG (2 waves: re half, im half) per block p.
    butterfly_local_conv<<<dim3(C_P), dim3(128), 0, stream>>>(
        x, Wrr, Wri, Wir, Wii, perm, out);
}